// Round 14
// baseline (288.073 us; speedup 1.0000x reference)
//
#include <hip/hip_runtime.h>
#include <math.h>

#define BATCH 8
#define CH 512
#define LEN 2048
#define NG 32
#define CPG 16

typedef unsigned short u16;
typedef __bf16 bf16x8 __attribute__((ext_vector_type(8)));
typedef float f32x16 __attribute__((ext_vector_type(16)));

__device__ __forceinline__ u16 f2bf(float f) {
    union { float f; unsigned u; } c; c.f = f;
    unsigned r = c.u + 0x7fffu + ((c.u >> 16) & 1u);   // RNE
    return (u16)(r >> 16);
}
__device__ __forceinline__ float bf2f(u16 h) {
    union { unsigned u; float f; } c; c.u = ((unsigned)h) << 16;
    return c.f;
}
__device__ __forceinline__ void gload16(const u16* g, u16* l) {
    __builtin_amdgcn_global_load_lds(
        (const __attribute__((address_space(1))) unsigned int*)g,
        (__attribute__((address_space(3))) unsigned int*)l, 16, 0, 0);
}

// ---------------------------------------------------------------------------
// fused pre-pass, one launch, independent block ranges:
//  [0,16)      zero rowsum (16 x 256 x float4)
//  [16,528)    wq/wk f32->bf16 into Wqk (rows 0-511 / 512-1023)
//  [528,592)   Wov = wo x wv in F32 (64x64 tile/block), rounded ONCE to bf16.
//              (algebraic fusion: out = x + E.(Wov.h)^T/rs + (Wo.bv+bo);
//               eliminates the final-projection GEMM entirely)
//  [592,594)   bias' = Wo.bv + bo (f32)
//  [594,1618)  GN stats partials: 4 slots per (b,g), plain stores
// ---------------------------------------------------------------------------
__global__ __launch_bounds__(256) void fused_pre(
    const float* __restrict__ x,
    const float* __restrict__ wq, const float* __restrict__ wk,
    const float* __restrict__ wv, const float* __restrict__ wo,
    const float* __restrict__ bv, const float* __restrict__ bo,
    u16* __restrict__ oq, u16* __restrict__ ok,
    u16* __restrict__ wov, float* __restrict__ biasp,
    float4* __restrict__ zbuf, float* __restrict__ stats) {
    const int blk = blockIdx.x;
    const int t = threadIdx.x;
    if (blk < 16) {
        zbuf[blk * 256 + t] = make_float4(0.f, 0.f, 0.f, 0.f);
    } else if (blk < 528) {
        const int wb = blk - 16;
        const float* s = (wb >> 8) ? wk : wq;
        u16* d = (wb >> 8) ? ok : oq;
        const int i = (wb & 255) * 256 + t;
        float4 f = ((const float4*)s)[i];
        ((ushort4*)d)[i] = make_ushort4(f2bf(f.x), f2bf(f.y), f2bf(f.z), f2bf(f.w));
    } else if (blk < 592) {
        // Wov[o][ci] = sum_c wo[o][c]*wv[c][ci]; 64x64 tile, 4x4 per thread
        const int b = blk - 528;
        const int o0 = (b >> 3) * 64, c0 = (b & 7) * 64;
        const int o = o0 + (t >> 4) * 4, c = c0 + (t & 15) * 4;
        float acc[4][4] = {};
        for (int k0 = 0; k0 < 512; k0 += 4) {
            float4 A4[4], B4[4];
            #pragma unroll
            for (int r = 0; r < 4; ++r) A4[r] = *(const float4*)&wo[(size_t)(o + r) * 512 + k0];
            #pragma unroll
            for (int kk = 0; kk < 4; ++kk) B4[kk] = *(const float4*)&wv[(size_t)(k0 + kk) * 512 + c];
            #pragma unroll
            for (int r = 0; r < 4; ++r) {
                const float ar[4] = {A4[r].x, A4[r].y, A4[r].z, A4[r].w};
                #pragma unroll
                for (int kk = 0; kk < 4; ++kk) {
                    acc[r][0] = fmaf(ar[kk], B4[kk].x, acc[r][0]);
                    acc[r][1] = fmaf(ar[kk], B4[kk].y, acc[r][1]);
                    acc[r][2] = fmaf(ar[kk], B4[kk].z, acc[r][2]);
                    acc[r][3] = fmaf(ar[kk], B4[kk].w, acc[r][3]);
                }
            }
        }
        #pragma unroll
        for (int r = 0; r < 4; ++r)
            *(ushort4*)&wov[(size_t)(o + r) * 512 + c] =
                make_ushort4(f2bf(acc[r][0]), f2bf(acc[r][1]), f2bf(acc[r][2]), f2bf(acc[r][3]));
    } else if (blk < 594) {
        const int o = (blk - 592) * 256 + t;
        float s = 0.f;
        for (int kk = 0; kk < 512; kk += 4) {
            float4 w4 = *(const float4*)&wo[(size_t)o * 512 + kk];
            float4 b4 = *(const float4*)&bv[kk];
            s = fmaf(w4.x, b4.x, fmaf(w4.y, b4.y, fmaf(w4.z, b4.z, fmaf(w4.w, b4.w, s))));
        }
        biasp[o] = s + bo[o];
    } else {
        const int sb = blk - 594;
        const int b = sb >> 7, g = (sb >> 2) & 31, sl = sb & 3;
        const float4* xp = (const float4*)(x + ((size_t)b * CH + (size_t)g * CPG) * LEN) + sl * 2048;
        float s = 0.f, s2 = 0.f;
        #pragma unroll
        for (int i = 0; i < 8; ++i) {
            float4 v = xp[t + i * 256];
            s += v.x + v.y + v.z + v.w;
            s2 = fmaf(v.x, v.x, fmaf(v.y, v.y, fmaf(v.z, v.z, fmaf(v.w, v.w, s2))));
        }
        #pragma unroll
        for (int off = 32; off > 0; off >>= 1) {
            s  += __shfl_down(s, off, 64);
            s2 += __shfl_down(s2, off, 64);
        }
        __shared__ float sm[2][4];
        const int lane = t & 63, wvv = t >> 6;
        if (lane == 0) { sm[0][wvv] = s; sm[1][wvv] = s2; }
        __syncthreads();
        if (t == 0) {
            const int base = (b * NG + g) * 4 + sl;
            stats[base]        = sm[0][0] + sm[0][1] + sm[0][2] + sm[0][3];
            stats[1024 + base] = sm[1][0] + sm[1][1] + sm[1][2] + sm[1][3];
        }
    }
}

// ---------------------------------------------------------------------------
// GN apply + [c][l]->[l][c] transpose; affine recomputed from stats partials.
// ---------------------------------------------------------------------------
__global__ __launch_bounds__(256) void gn_apply_t(const float* __restrict__ x,
                                                  const float* __restrict__ stats,
                                                  const float* __restrict__ gw,
                                                  const float* __restrict__ gb,
                                                  u16* __restrict__ Ht) {
    __shared__ float tile[64][65];
    const int b = blockIdx.z, c0 = blockIdx.y * 64, l0 = blockIdx.x * 64;
    const int t = threadIdx.x;
    const int rid = t >> 4, q = t & 15;
    const float inv = 1.f / (CPG * LEN);
    #pragma unroll
    for (int pass = 0; pass < 4; ++pass) {
        const int c = rid + pass * 16;
        const int ca = c0 + c;
        const int base = (b * NG + (ca >> 4)) * 4;
        const float S  = stats[base + 0] + stats[base + 1] + stats[base + 2] + stats[base + 3];
        const float S2 = stats[1024 + base + 0] + stats[1024 + base + 1]
                       + stats[1024 + base + 2] + stats[1024 + base + 3];
        const float mean = S * inv;
        const float var  = S2 * inv - mean * mean;
        const float a  = rsqrtf(var + 1e-6f) * gw[ca];
        const float sh = gb[ca] - mean * a;
        const float4 v = *(const float4*)&x[((size_t)b * CH + ca) * LEN + l0 + q * 4];
        tile[c][q * 4 + 0] = v.x * a + sh;
        tile[c][q * 4 + 1] = v.y * a + sh;
        tile[c][q * 4 + 2] = v.z * a + sh;
        tile[c][q * 4 + 3] = v.w * a + sh;
    }
    __syncthreads();
    #pragma unroll
    for (int pass = 0; pass < 4; ++pass) {
        const int l = rid + pass * 16;
        ushort4 o;
        o.x = f2bf(tile[q * 4 + 0][l]);
        o.y = f2bf(tile[q * 4 + 1][l]);
        o.z = f2bf(tile[q * 4 + 2][l]);
        o.w = f2bf(tile[q * 4 + 3][l]);
        *(ushort4*)&Ht[((size_t)b * LEN + l0 + l) * CH + c0 + q * 4] = o;
    }
}

// ---------------------------------------------------------------------------
// r4 GEMM core (proven): 128x128 tile, BK=64, single-buffer, 2-barrier,
// 256 thr / 4 waves, 4 blocks/CU. XOR-swizzled k-chunks via global source.
//  EPI_QK : bf16; (Out,bias)/(Out2,bias2) by m half; +bias[m]
//  EPI_PVF: f32; PV'' = E.V'^T; *1/rowsum[m-row] + bias'[n] + residual.
//           XCD remap (batch->XCD, matches Sb producer) + n-fast in-XCD
//           order (4 consecutive blocks share one Sb i-panel; V' L2-fit).
// ---------------------------------------------------------------------------
#define EPI_QK   0
#define EPI_PVF  5

template <int MODE>
__global__ __launch_bounds__(256, 4) void gemm_bt(
    const u16* __restrict__ A, int lda, long long sA,
    const u16* __restrict__ B, int ldb, long long sB,
    void* __restrict__ Out, void* __restrict__ Out2,
    int ldo, long long sO,
    const float* __restrict__ bias, const float* __restrict__ bias2,
    const float* __restrict__ res, long long sR,
    float* __restrict__ rsum, long long sRS,
    int K, float alpha) {
    __shared__ u16 As[128 * 64];
    __shared__ u16 Bs[128 * 64];

    int bz, by, bx;
    if (MODE == EPI_PVF) {
        const int gx = gridDim.x, gy = gridDim.y;          // 4, 16
        int flat = (blockIdx.z * gy + blockIdx.y) * gx + blockIdx.x;
        const int nbk = gx * gy * (int)gridDim.z;          // 512
        flat = (flat & 7) * (nbk >> 3) + (flat >> 3);
        bz = flat / (gx * gy);
        const int rr = flat - bz * gx * gy;
        bx = rr & 3;                                       // n-fast
        by = rr >> 2;
    } else {
        bz = blockIdx.z; by = blockIdx.y; bx = blockIdx.x;
    }
    const int n0 = bx * 128, m0 = by * 128;
    A += (size_t)bz * sA;
    B += (size_t)bz * sB;
    const int t = threadIdx.x;
    const int lane = t & 63, wid = t >> 6;

    const int rowL = t >> 3, kq = (t & 7) ^ (rowL & 7);
    unsigned aoff = (unsigned)((m0 + rowL) * lda + kq * 8);
    unsigned boff = (unsigned)((n0 + rowL) * ldb + kq * 8);
    u16* const lds_dst_a = As + t * 8;
    u16* const lds_dst_b = Bs + t * 8;

    f32x16 acc[2][2];
    #pragma unroll
    for (int i = 0; i < 2; ++i)
        #pragma unroll
        for (int j = 0; j < 2; ++j)
            acc[i][j] = (f32x16)(0.f);

    const int col = lane & 31, half = lane >> 5;
    const int wm = (wid & 1) * 64, wn = (wid >> 1) * 64;
    const int mf = wm + col, nf = wn + col;
    const int mswz = mf & 7, nswz = nf & 7;

    for (int k0 = 0; k0 < K; k0 += 64) {
        #pragma unroll
        for (int g = 0; g < 4; ++g) {
            gload16(A + aoff + g * (32 * lda), lds_dst_a + g * 2048);
            gload16(B + boff + g * (32 * ldb), lds_dst_b + g * 2048);
        }
        aoff += 64; boff += 64;
        __syncthreads();
        #pragma unroll
        for (int ks = 0; ks < 4; ++ks) {
            const int kcA = ((ks * 2 + half) ^ mswz) * 8;
            const int kcB = ((ks * 2 + half) ^ nswz) * 8;
            bf16x8 a0 = *(const bf16x8*)(As + (mf)      * 64 + kcA);
            bf16x8 a1 = *(const bf16x8*)(As + (mf + 32) * 64 + kcA);
            bf16x8 b0 = *(const bf16x8*)(Bs + (nf)      * 64 + kcB);
            bf16x8 b1 = *(const bf16x8*)(Bs + (nf + 32) * 64 + kcB);
            acc[0][0] = __builtin_amdgcn_mfma_f32_32x32x16_bf16(a0, b0, acc[0][0], 0, 0, 0);
            acc[0][1] = __builtin_amdgcn_mfma_f32_32x32x16_bf16(a0, b1, acc[0][1], 0, 0, 0);
            acc[1][0] = __builtin_amdgcn_mfma_f32_32x32x16_bf16(a1, b0, acc[1][0], 0, 0, 0);
            acc[1][1] = __builtin_amdgcn_mfma_f32_32x32x16_bf16(a1, b1, acc[1][1], 0, 0, 0);
        }
        __syncthreads();
    }

    // C/D: col = lane&31 (n), row = (reg&3) + 8*(reg>>2) + 4*half (+ 32*i_m)
    if (MODE == EPI_PVF) {
        float* O = (float*)Out + (size_t)bz * sO;
        const float* R = res + (size_t)bz * sR;
        const float* RS = rsum + (size_t)bz * sRS;
        #pragma unroll
        for (int im = 0; im < 2; ++im)
            #pragma unroll
            for (int g4 = 0; g4 < 4; ++g4) {
                const int mb = m0 + wm + im * 32 + g4 * 8 + half * 4;
                const float4 rs4 = *(const float4*)&RS[mb];
                const float4 iv = make_float4(1.f / rs4.x, 1.f / rs4.y, 1.f / rs4.z, 1.f / rs4.w);
                #pragma unroll
                for (int jn = 0; jn < 2; ++jn) {
                    const int n = n0 + wn + jn * 32 + col;
                    const float bb = bias[n];
                    const size_t base = (size_t)n * ldo + mb;
                    const float4 r4 = *(const float4*)&R[base];
                    float4 o4;
                    o4.x = acc[im][jn][g4 * 4 + 0] * iv.x + bb + r4.x;
                    o4.y = acc[im][jn][g4 * 4 + 1] * iv.y + bb + r4.y;
                    o4.z = acc[im][jn][g4 * 4 + 2] * iv.z + bb + r4.z;
                    o4.w = acc[im][jn][g4 * 4 + 3] * iv.w + bb + r4.w;
                    *(float4*)&O[base] = o4;
                }
            }
    } else {   // EPI_QK
        const bool hi = (m0 & 512) != 0;
        u16* O = (u16*)(hi ? Out2 : Out) + (size_t)bz * sO;
        const float* bi = hi ? bias2 : bias;
        const int mbase = (m0 & 511) + wm;
        #pragma unroll
        for (int im = 0; im < 2; ++im)
            #pragma unroll
            for (int g4 = 0; g4 < 4; ++g4) {
                const int mb = mbase + im * 32 + g4 * 8 + half * 4;
                const float4 bm = *(const float4*)&bi[mb];
                #pragma unroll
                for (int jn = 0; jn < 2; ++jn) {
                    const int n = n0 + wn + jn * 32 + col;
                    ushort4 pk = make_ushort4(f2bf(acc[im][jn][g4 * 4 + 0] + bm.x),
                                              f2bf(acc[im][jn][g4 * 4 + 1] + bm.y),
                                              f2bf(acc[im][jn][g4 * 4 + 2] + bm.z),
                                              f2bf(acc[im][jn][g4 * 4 + 3] + bm.w));
                    *(ushort4*)&O[(size_t)n * ldo + mb] = pk;
                }
            }
    }
}

// ---------------------------------------------------------------------------
// scores + V' in ONE launch (2560 blocks), r12-proven geometry.
//  blocks [0,2048):   scores  A=Kt B=Qt -> Sb=exp(scale*S), rowsum atomics,
//                     bijective XCD remap (batch->XCD).
//  blocks [2048,2560): V'     A=Ht B=Wov -> V'b[o][l] (plain bf16; the bv
//                     contribution is exact via bias' in the PV'' epilogue).
// ---------------------------------------------------------------------------
__global__ __launch_bounds__(256, 4) void gemm_sv(
    const u16* __restrict__ Kt, const u16* __restrict__ Qt,
    const u16* __restrict__ Ht, const u16* __restrict__ Wov,
    u16* __restrict__ Sb, u16* __restrict__ Vb,
    float* __restrict__ rowsum, float alpha) {
    __shared__ u16 As[128 * 64];
    __shared__ u16 Bs[128 * 64];

    const long long sH = (long long)LEN * CH;
    const int blk = blockIdx.x;
    const bool isV = blk >= 2048;
    int bz, by, bx;
    const u16 *A, *B;
    u16* O;
    if (!isV) {
        int flat = (blk & 7) * 256 + (blk >> 3);   // bijective XCD remap
        bz = flat >> 8;
        const int rr = flat & 255;
        by = rr >> 4; bx = rr & 15;
        A = Kt + (size_t)bz * sH;
        B = Qt + (size_t)bz * sH;
        O = Sb + (size_t)bz * ((long long)LEN * LEN);
    } else {
        const int v = blk - 2048;
        bz = v >> 6;
        const int rr = v & 63;
        by = rr >> 2; bx = rr & 3;
        A = Ht + (size_t)bz * sH;
        B = Wov;
        O = Vb + (size_t)bz * ((long long)CH * LEN);
    }

    const int n0 = bx * 128, m0 = by * 128;
    const int t = threadIdx.x;
    const int lane = t & 63, wid = t >> 6;

    const int rowL = t >> 3, kq = (t & 7) ^ (rowL & 7);
    unsigned aoff = (unsigned)((m0 + rowL) * CH + kq * 8);
    unsigned boff = (unsigned)((n0 + rowL) * CH + kq * 8);
    u16* const lds_dst_a = As + t * 8;
    u16* const lds_dst_b = Bs + t * 8;

    f32x16 acc[2][2];
    #pragma unroll
    for (int i = 0; i < 2; ++i)
        #pragma unroll
        for (int j = 0; j < 2; ++j)
            acc[i][j] = (f32x16)(0.f);

    const int col = lane & 31, half = lane >> 5;
    const int wm = (wid & 1) * 64, wn = (wid >> 1) * 64;
    const int mf = wm + col, nf = wn + col;
    const int mswz = mf & 7, nswz = nf & 7;

    for (int k0 = 0; k0 < CH; k0 += 64) {
        #pragma unroll
        for (int g = 0; g < 4; ++g) {
            gload16(A + aoff + g * (32 * CH), lds_dst_a + g * 2048);
            gload16(B + boff + g * (32 * CH), lds_dst_b + g * 2048);
        }
        aoff += 64; boff += 64;
        __syncthreads();
        #pragma unroll
        for (int ks = 0; ks < 4; ++ks) {
            const int kcA = ((ks * 2 + half) ^ mswz) * 8;
            const int kcB = ((ks * 2 + half) ^ nswz) * 8;
            bf16x8 a0 = *(const bf16x8*)(As + (mf)      * 64 + kcA);
            bf16x8 a1 = *(const bf16x8*)(As + (mf + 32) * 64 + kcA);
            bf16x8 b0 = *(const bf16x8*)(Bs + (nf)      * 64 + kcB);
            bf16x8 b1 = *(const bf16x8*)(Bs + (nf + 32) * 64 + kcB);
            acc[0][0] = __builtin_amdgcn_mfma_f32_32x32x16_bf16(a0, b0, acc[0][0], 0, 0, 0);
            acc[0][1] = __builtin_amdgcn_mfma_f32_32x32x16_bf16(a0, b1, acc[0][1], 0, 0, 0);
            acc[1][0] = __builtin_amdgcn_mfma_f32_32x32x16_bf16(a1, b0, acc[1][0], 0, 0, 0);
            acc[1][1] = __builtin_amdgcn_mfma_f32_32x32x16_bf16(a1, b1, acc[1][1], 0, 0, 0);
        }
        __syncthreads();
    }

    if (!isV) {
        float* RS = rowsum + (size_t)bz * LEN;
        float psum[2] = {0.f, 0.f};
        #pragma unroll
        for (int im = 0; im < 2; ++im)
            #pragma unroll
            for (int g4 = 0; g4 < 4; ++g4) {
                const int mb = m0 + wm + im * 32 + g4 * 8 + half * 4;
                #pragma unroll
                for (int jn = 0; jn < 2; ++jn) {
                    const int n = n0 + wn + jn * 32 + col;
                    u16 h0 = f2bf(__expf(acc[im][jn][g4 * 4 + 0] * alpha));
                    u16 h1 = f2bf(__expf(acc[im][jn][g4 * 4 + 1] * alpha));
                    u16 h2 = f2bf(__expf(acc[im][jn][g4 * 4 + 2] * alpha));
                    u16 h3 = f2bf(__expf(acc[im][jn][g4 * 4 + 3] * alpha));
                    psum[jn] += bf2f(h0) + bf2f(h1) + bf2f(h2) + bf2f(h3);
                    *(ushort4*)&O[(size_t)n * LEN + mb] = make_ushort4(h0, h1, h2, h3);
                }
            }
        #pragma unroll
        for (int jn = 0; jn < 2; ++jn) psum[jn] += __shfl_xor(psum[jn], 32, 64);
        if (half == 0) {
            #pragma unroll
            for (int jn = 0; jn < 2; ++jn)
                atomicAdd(&RS[n0 + wn + jn * 32 + col], psum[jn]);
        }
    } else {
        #pragma unroll
        for (int im = 0; im < 2; ++im)
            #pragma unroll
            for (int g4 = 0; g4 < 4; ++g4) {
                const int mb = m0 + wm + im * 32 + g4 * 8 + half * 4;
                #pragma unroll
                for (int jn = 0; jn < 2; ++jn) {
                    const int n = n0 + wn + jn * 32 + col;
                    ushort4 pk = make_ushort4(f2bf(acc[im][jn][g4 * 4 + 0]),
                                              f2bf(acc[im][jn][g4 * 4 + 1]),
                                              f2bf(acc[im][jn][g4 * 4 + 2]),
                                              f2bf(acc[im][jn][g4 * 4 + 3]));
                    *(ushort4*)&O[(size_t)n * LEN + mb] = pk;
                }
            }
    }
}

// ---------------------------------------------------------------------------
extern "C" void kernel_launch(void* const* d_in, const int* in_sizes, int n_in,
                              void* d_out, int out_size, void* d_ws, size_t ws_size,
                              hipStream_t stream) {
    const float* x    = (const float*)d_in[0];
    const float* gn_w = (const float*)d_in[1];
    const float* gn_b = (const float*)d_in[2];
    const float* wq   = (const float*)d_in[3];
    const float* bq   = (const float*)d_in[4];
    const float* wk   = (const float*)d_in[5];
    const float* bk   = (const float*)d_in[6];
    const float* wv   = (const float*)d_in[7];
    const float* bv   = (const float*)d_in[8];
    const float* wo   = (const float*)d_in[9];
    const float* bo   = (const float*)d_in[10];
    float* out = (float*)d_out;

    char* p = (char*)d_ws;
    const size_t WSZ = (size_t)CH * CH * 2;
    const size_t HSZ = (size_t)BATCH * CH * LEN * 2;
    u16* Wqk = (u16*)p; p += 2 * WSZ;   // rows 0-511 = Wq, 512-1023 = Wk
    u16* Wov = (u16*)p; p += WSZ;       // (Wo.Wv) bf16 [o][c']
    float* biasp = (float*)p; p += WSZ; // bias' = Wo.bv + bo (512 f32; slot reused)
    u16* Ht  = (u16*)p; p += HSZ;   // GN out [b][l][c]
    u16* Qt  = (u16*)p; p += HSZ;   // [b][l][c]
    u16* Kt  = (u16*)p; p += HSZ;   // [b][l][c]
    u16* Vb  = (u16*)p; p += HSZ;   // V' [b][o][l]
    u16* Sb  = (u16*)p; p += (size_t)BATCH * LEN * LEN * 2;  // exp(scores)
    float* rowsum = (float*)p; p += (size_t)BATCH * LEN * 4; // 16384 f32, zeroed
    float* stats  = (float*)p;      // 2048 f32: S partials | S2 partials

    const long long sH = (long long)LEN * CH;
    const long long sV = (long long)CH * LEN;
    const float scale = 0.04419417382415922f;   // 512^-0.5

    // pre-pass: zero(16) | wq/wk conv(512) | Wov f32-GEMM(64) | bias'(2) | stats(1024)
    fused_pre<<<1618, 256, 0, stream>>>(x, wq, wk, wv, wo, bv, bo,
                                        Wqk, Wqk + (size_t)CH * CH, Wov, biasp,
                                        (float4*)rowsum, stats);
    gn_apply_t<<<dim3(LEN / 64, CH / 64, BATCH), 256, 0, stream>>>(x, stats, gn_w, gn_b, Ht);

    // Q+K fused: A=Wqk (m=o), B=Ht (n=l) -> Qt/Kt[l][o] packed in o
    gemm_bt<EPI_QK><<<dim3(16, 8, 8), 256, 0, stream>>>(
        Wqk, CH, 0, Ht, CH, sH, Qt, Kt, CH, sH, bq, bk, nullptr, 0, nullptr, 0, CH, 0.f);
    // scores (2048 blocks, XCD-remapped) + V' (512 blocks) in one launch
    gemm_sv<<<2560, 256, 0, stream>>>(Kt, Qt, Ht, Wov, Sb, Vb, rowsum, scale);
    // PV'' (replaces PV + final): A=Sb (m=i), B=V'b (n=o) ->
    //   out[o][i] = acc/rs[i] + bias'[o] + x[o][i]  (f32, residual fused)
    gemm_bt<EPI_PVF><<<dim3(4, 16, 8), 256, 0, stream>>>(
        Sb, LEN, (long long)LEN * LEN, Vb, LEN, sV, out, nullptr, LEN, sV,
        biasp, nullptr, x, sV, rowsum, LEN, LEN, 0.f);
}

// Round 15
// 287.965 us; speedup vs baseline: 1.0004x; 1.0004x over previous
//
#include <hip/hip_runtime.h>
#include <math.h>

#define BATCH 8
#define CH 512
#define LEN 2048
#define NG 32
#define CPG 16

typedef unsigned short u16;
typedef __bf16 bf16x8 __attribute__((ext_vector_type(8)));
typedef float f32x16 __attribute__((ext_vector_type(16)));

__device__ __forceinline__ u16 f2bf(float f) {
    union { float f; unsigned u; } c; c.f = f;
    unsigned r = c.u + 0x7fffu + ((c.u >> 16) & 1u);   // RNE
    return (u16)(r >> 16);
}
__device__ __forceinline__ float bf2f(u16 h) {
    union { unsigned u; float f; } c; c.u = ((unsigned)h) << 16;
    return c.f;
}
__device__ __forceinline__ void gload16(const u16* g, u16* l) {
    __builtin_amdgcn_global_load_lds(
        (const __attribute__((address_space(1))) unsigned int*)g,
        (__attribute__((address_space(3))) unsigned int*)l, 16, 0, 0);
}

// ---------------------------------------------------------------------------
// Wov = wo x wv (f32 accum, ONE bf16 round) + bias' = Wo.bv + bo.
// SEPARATE kernel (r14 lesson: co-compiled into fused_pre, the register
// allocator sized the whole kernel at 32 VGPR -> this branch spilled to
// scratch, 75us. Own kernel = own regalloc, ~30 VGPR, no spill).
//  blk [0,256): 32x32 tile; thread = (row t>>3, 4-col strip (t&7)*4); K-step 4.
//  blk [256,258): bias'.
// ---------------------------------------------------------------------------
__global__ __launch_bounds__(256) void wov_bias(
    const float* __restrict__ wv, const float* __restrict__ wo,
    const float* __restrict__ bv, const float* __restrict__ bo,
    u16* __restrict__ wov, float* __restrict__ biasp) {
    const int blk = blockIdx.x;
    const int t = threadIdx.x;
    if (blk < 256) {
        const int o = (blk >> 4) * 32 + (t >> 3);
        const int c = (blk & 15) * 32 + (t & 7) * 4;
        float a0 = 0.f, a1 = 0.f, a2 = 0.f, a3 = 0.f;
        for (int k0 = 0; k0 < 512; k0 += 4) {
            const float4 A4 = *(const float4*)&wo[(size_t)o * 512 + k0];
            const float4 B0 = *(const float4*)&wv[(size_t)(k0 + 0) * 512 + c];
            const float4 B1 = *(const float4*)&wv[(size_t)(k0 + 1) * 512 + c];
            const float4 B2 = *(const float4*)&wv[(size_t)(k0 + 2) * 512 + c];
            const float4 B3 = *(const float4*)&wv[(size_t)(k0 + 3) * 512 + c];
            a0 = fmaf(A4.x, B0.x, fmaf(A4.y, B1.x, fmaf(A4.z, B2.x, fmaf(A4.w, B3.x, a0))));
            a1 = fmaf(A4.x, B0.y, fmaf(A4.y, B1.y, fmaf(A4.z, B2.y, fmaf(A4.w, B3.y, a1))));
            a2 = fmaf(A4.x, B0.z, fmaf(A4.y, B1.z, fmaf(A4.z, B2.z, fmaf(A4.w, B3.z, a2))));
            a3 = fmaf(A4.x, B0.w, fmaf(A4.y, B1.w, fmaf(A4.z, B2.w, fmaf(A4.w, B3.w, a3))));
        }
        *(ushort4*)&wov[(size_t)o * 512 + c] =
            make_ushort4(f2bf(a0), f2bf(a1), f2bf(a2), f2bf(a3));
    } else {
        const int o = (blk - 256) * 256 + t;
        float s = 0.f;
        for (int kk = 0; kk < 512; kk += 4) {
            float4 w4 = *(const float4*)&wo[(size_t)o * 512 + kk];
            float4 b4 = *(const float4*)&bv[kk];
            s = fmaf(w4.x, b4.x, fmaf(w4.y, b4.y, fmaf(w4.z, b4.z, fmaf(w4.w, b4.w, s))));
        }
        biasp[o] = s + bo[o];
    }
}

// ---------------------------------------------------------------------------
// fused pre-pass (streaming only; r14's Wov blocks moved out):
//  [0,16)      zero rowsum (16 x 256 x float4)
//  [16,528)    wq/wk f32->bf16 into Wqk (rows 0-511 / 512-1023)
//  [528,1552)  GN stats partials: 4 slots per (b,g), plain stores
// ---------------------------------------------------------------------------
__global__ __launch_bounds__(256) void fused_pre(
    const float* __restrict__ x,
    const float* __restrict__ wq, const float* __restrict__ wk,
    u16* __restrict__ oq, u16* __restrict__ ok,
    float4* __restrict__ zbuf, float* __restrict__ stats) {
    const int blk = blockIdx.x;
    const int t = threadIdx.x;
    if (blk < 16) {
        zbuf[blk * 256 + t] = make_float4(0.f, 0.f, 0.f, 0.f);
    } else if (blk < 528) {
        const int wb = blk - 16;
        const float* s = (wb >> 8) ? wk : wq;
        u16* d = (wb >> 8) ? ok : oq;
        const int i = (wb & 255) * 256 + t;
        float4 f = ((const float4*)s)[i];
        ((ushort4*)d)[i] = make_ushort4(f2bf(f.x), f2bf(f.y), f2bf(f.z), f2bf(f.w));
    } else {
        const int sb = blk - 528;
        const int b = sb >> 7, g = (sb >> 2) & 31, sl = sb & 3;
        const float4* xp = (const float4*)(x + ((size_t)b * CH + (size_t)g * CPG) * LEN) + sl * 2048;
        float s = 0.f, s2 = 0.f;
        #pragma unroll
        for (int i = 0; i < 8; ++i) {
            float4 v = xp[t + i * 256];
            s += v.x + v.y + v.z + v.w;
            s2 = fmaf(v.x, v.x, fmaf(v.y, v.y, fmaf(v.z, v.z, fmaf(v.w, v.w, s2))));
        }
        #pragma unroll
        for (int off = 32; off > 0; off >>= 1) {
            s  += __shfl_down(s, off, 64);
            s2 += __shfl_down(s2, off, 64);
        }
        __shared__ float sm[2][4];
        const int lane = t & 63, wvv = t >> 6;
        if (lane == 0) { sm[0][wvv] = s; sm[1][wvv] = s2; }
        __syncthreads();
        if (t == 0) {
            const int base = (b * NG + g) * 4 + sl;
            stats[base]        = sm[0][0] + sm[0][1] + sm[0][2] + sm[0][3];
            stats[1024 + base] = sm[1][0] + sm[1][1] + sm[1][2] + sm[1][3];
        }
    }
}

// ---------------------------------------------------------------------------
// GN apply + [c][l]->[l][c] transpose; affine recomputed from stats partials.
// ---------------------------------------------------------------------------
__global__ __launch_bounds__(256) void gn_apply_t(const float* __restrict__ x,
                                                  const float* __restrict__ stats,
                                                  const float* __restrict__ gw,
                                                  const float* __restrict__ gb,
                                                  u16* __restrict__ Ht) {
    __shared__ float tile[64][65];
    const int b = blockIdx.z, c0 = blockIdx.y * 64, l0 = blockIdx.x * 64;
    const int t = threadIdx.x;
    const int rid = t >> 4, q = t & 15;
    const float inv = 1.f / (CPG * LEN);
    #pragma unroll
    for (int pass = 0; pass < 4; ++pass) {
        const int c = rid + pass * 16;
        const int ca = c0 + c;
        const int base = (b * NG + (ca >> 4)) * 4;
        const float S  = stats[base + 0] + stats[base + 1] + stats[base + 2] + stats[base + 3];
        const float S2 = stats[1024 + base + 0] + stats[1024 + base + 1]
                       + stats[1024 + base + 2] + stats[1024 + base + 3];
        const float mean = S * inv;
        const float var  = S2 * inv - mean * mean;
        const float a  = rsqrtf(var + 1e-6f) * gw[ca];
        const float sh = gb[ca] - mean * a;
        const float4 v = *(const float4*)&x[((size_t)b * CH + ca) * LEN + l0 + q * 4];
        tile[c][q * 4 + 0] = v.x * a + sh;
        tile[c][q * 4 + 1] = v.y * a + sh;
        tile[c][q * 4 + 2] = v.z * a + sh;
        tile[c][q * 4 + 3] = v.w * a + sh;
    }
    __syncthreads();
    #pragma unroll
    for (int pass = 0; pass < 4; ++pass) {
        const int l = rid + pass * 16;
        ushort4 o;
        o.x = f2bf(tile[q * 4 + 0][l]);
        o.y = f2bf(tile[q * 4 + 1][l]);
        o.z = f2bf(tile[q * 4 + 2][l]);
        o.w = f2bf(tile[q * 4 + 3][l]);
        *(ushort4*)&Ht[((size_t)b * LEN + l0 + l) * CH + c0 + q * 4] = o;
    }
}

// ---------------------------------------------------------------------------
// r4 GEMM core (proven): 128x128 tile, BK=64, single-buffer, 2-barrier,
// 256 thr / 4 waves, 4 blocks/CU. XOR-swizzled k-chunks via global source.
//  EPI_QK : bf16; (Out,bias)/(Out2,bias2) by m half; +bias[m]
//  EPI_PVF: f32; PV'' = E.V'^T; *1/rowsum[m-row] + bias'[n] + residual.
//           XCD remap (batch->XCD, matches Sb producer) + n-fast in-XCD order.
// ---------------------------------------------------------------------------
#define EPI_QK   0
#define EPI_PVF  5

template <int MODE>
__global__ __launch_bounds__(256, 4) void gemm_bt(
    const u16* __restrict__ A, int lda, long long sA,
    const u16* __restrict__ B, int ldb, long long sB,
    void* __restrict__ Out, void* __restrict__ Out2,
    int ldo, long long sO,
    const float* __restrict__ bias, const float* __restrict__ bias2,
    const float* __restrict__ res, long long sR,
    float* __restrict__ rsum, long long sRS,
    int K, float alpha) {
    __shared__ u16 As[128 * 64];
    __shared__ u16 Bs[128 * 64];

    int bz, by, bx;
    if (MODE == EPI_PVF) {
        const int gx = gridDim.x, gy = gridDim.y;          // 4, 16
        int flat = (blockIdx.z * gy + blockIdx.y) * gx + blockIdx.x;
        const int nbk = gx * gy * (int)gridDim.z;          // 512
        flat = (flat & 7) * (nbk >> 3) + (flat >> 3);
        bz = flat / (gx * gy);
        const int rr = flat - bz * gx * gy;
        bx = rr & 3;                                       // n-fast
        by = rr >> 2;
    } else {
        bz = blockIdx.z; by = blockIdx.y; bx = blockIdx.x;
    }
    const int n0 = bx * 128, m0 = by * 128;
    A += (size_t)bz * sA;
    B += (size_t)bz * sB;
    const int t = threadIdx.x;
    const int lane = t & 63, wid = t >> 6;

    const int rowL = t >> 3, kq = (t & 7) ^ (rowL & 7);
    unsigned aoff = (unsigned)((m0 + rowL) * lda + kq * 8);
    unsigned boff = (unsigned)((n0 + rowL) * ldb + kq * 8);
    u16* const lds_dst_a = As + t * 8;
    u16* const lds_dst_b = Bs + t * 8;

    f32x16 acc[2][2];
    #pragma unroll
    for (int i = 0; i < 2; ++i)
        #pragma unroll
        for (int j = 0; j < 2; ++j)
            acc[i][j] = (f32x16)(0.f);

    const int col = lane & 31, half = lane >> 5;
    const int wm = (wid & 1) * 64, wn = (wid >> 1) * 64;
    const int mf = wm + col, nf = wn + col;
    const int mswz = mf & 7, nswz = nf & 7;

    for (int k0 = 0; k0 < K; k0 += 64) {
        #pragma unroll
        for (int g = 0; g < 4; ++g) {
            gload16(A + aoff + g * (32 * lda), lds_dst_a + g * 2048);
            gload16(B + boff + g * (32 * ldb), lds_dst_b + g * 2048);
        }
        aoff += 64; boff += 64;
        __syncthreads();
        #pragma unroll
        for (int ks = 0; ks < 4; ++ks) {
            const int kcA = ((ks * 2 + half) ^ mswz) * 8;
            const int kcB = ((ks * 2 + half) ^ nswz) * 8;
            bf16x8 a0 = *(const bf16x8*)(As + (mf)      * 64 + kcA);
            bf16x8 a1 = *(const bf16x8*)(As + (mf + 32) * 64 + kcA);
            bf16x8 b0 = *(const bf16x8*)(Bs + (nf)      * 64 + kcB);
            bf16x8 b1 = *(const bf16x8*)(Bs + (nf + 32) * 64 + kcB);
            acc[0][0] = __builtin_amdgcn_mfma_f32_32x32x16_bf16(a0, b0, acc[0][0], 0, 0, 0);
            acc[0][1] = __builtin_amdgcn_mfma_f32_32x32x16_bf16(a0, b1, acc[0][1], 0, 0, 0);
            acc[1][0] = __builtin_amdgcn_mfma_f32_32x32x16_bf16(a1, b0, acc[1][0], 0, 0, 0);
            acc[1][1] = __builtin_amdgcn_mfma_f32_32x32x16_bf16(a1, b1, acc[1][1], 0, 0, 0);
        }
        __syncthreads();
    }

    // C/D: col = lane&31 (n), row = (reg&3) + 8*(reg>>2) + 4*half (+ 32*i_m)
    if (MODE == EPI_PVF) {
        float* O = (float*)Out + (size_t)bz * sO;
        const float* R = res + (size_t)bz * sR;
        const float* RS = rsum + (size_t)bz * sRS;
        #pragma unroll
        for (int im = 0; im < 2; ++im)
            #pragma unroll
            for (int g4 = 0; g4 < 4; ++g4) {
                const int mb = m0 + wm + im * 32 + g4 * 8 + half * 4;
                const float4 rs4 = *(const float4*)&RS[mb];
                const float4 iv = make_float4(1.f / rs4.x, 1.f / rs4.y, 1.f / rs4.z, 1.f / rs4.w);
                #pragma unroll
                for (int jn = 0; jn < 2; ++jn) {
                    const int n = n0 + wn + jn * 32 + col;
                    const float bb = bias[n];
                    const size_t base = (size_t)n * ldo + mb;
                    const float4 r4 = *(const float4*)&R[base];
                    float4 o4;
                    o4.x = acc[im][jn][g4 * 4 + 0] * iv.x + bb + r4.x;
                    o4.y = acc[im][jn][g4 * 4 + 1] * iv.y + bb + r4.y;
                    o4.z = acc[im][jn][g4 * 4 + 2] * iv.z + bb + r4.z;
                    o4.w = acc[im][jn][g4 * 4 + 3] * iv.w + bb + r4.w;
                    *(float4*)&O[base] = o4;
                }
            }
    } else {   // EPI_QK
        const bool hi = (m0 & 512) != 0;
        u16* O = (u16*)(hi ? Out2 : Out) + (size_t)bz * sO;
        const float* bi = hi ? bias2 : bias;
        const int mbase = (m0 & 511) + wm;
        #pragma unroll
        for (int im = 0; im < 2; ++im)
            #pragma unroll
            for (int g4 = 0; g4 < 4; ++g4) {
                const int mb = mbase + im * 32 + g4 * 8 + half * 4;
                const float4 bm = *(const float4*)&bi[mb];
                #pragma unroll
                for (int jn = 0; jn < 2; ++jn) {
                    const int n = n0 + wn + jn * 32 + col;
                    ushort4 pk = make_ushort4(f2bf(acc[im][jn][g4 * 4 + 0] + bm.x),
                                              f2bf(acc[im][jn][g4 * 4 + 1] + bm.y),
                                              f2bf(acc[im][jn][g4 * 4 + 2] + bm.z),
                                              f2bf(acc[im][jn][g4 * 4 + 3] + bm.w));
                    *(ushort4*)&O[(size_t)n * ldo + mb] = pk;
                }
            }
    }
}

// ---------------------------------------------------------------------------
// scores + V' in ONE launch (2560 blocks), r12-proven geometry.
//  blocks [0,2048):   scores  A=Kt B=Qt -> Sb=exp(scale*S), rowsum atomics,
//                     bijective XCD remap (batch->XCD).
//  blocks [2048,2560): V'     A=Ht B=Wov -> V'b[o][l] bf16.
// ---------------------------------------------------------------------------
__global__ __launch_bounds__(256, 4) void gemm_sv(
    const u16* __restrict__ Kt, const u16* __restrict__ Qt,
    const u16* __restrict__ Ht, const u16* __restrict__ Wov,
    u16* __restrict__ Sb, u16* __restrict__ Vb,
    float* __restrict__ rowsum, float alpha) {
    __shared__ u16 As[128 * 64];
    __shared__ u16 Bs[128 * 64];

    const long long sH = (long long)LEN * CH;
    const int blk = blockIdx.x;
    const bool isV = blk >= 2048;
    int bz, by, bx;
    const u16 *A, *B;
    u16* O;
    if (!isV) {
        int flat = (blk & 7) * 256 + (blk >> 3);   // bijective XCD remap
        bz = flat >> 8;
        const int rr = flat & 255;
        by = rr >> 4; bx = rr & 15;
        A = Kt + (size_t)bz * sH;
        B = Qt + (size_t)bz * sH;
        O = Sb + (size_t)bz * ((long long)LEN * LEN);
    } else {
        const int v = blk - 2048;
        bz = v >> 6;
        const int rr = v & 63;
        by = rr >> 2; bx = rr & 3;
        A = Ht + (size_t)bz * sH;
        B = Wov;
        O = Vb + (size_t)bz * ((long long)CH * LEN);
    }

    const int n0 = bx * 128, m0 = by * 128;
    const int t = threadIdx.x;
    const int lane = t & 63, wid = t >> 6;

    const int rowL = t >> 3, kq = (t & 7) ^ (rowL & 7);
    unsigned aoff = (unsigned)((m0 + rowL) * CH + kq * 8);
    unsigned boff = (unsigned)((n0 + rowL) * CH + kq * 8);
    u16* const lds_dst_a = As + t * 8;
    u16* const lds_dst_b = Bs + t * 8;

    f32x16 acc[2][2];
    #pragma unroll
    for (int i = 0; i < 2; ++i)
        #pragma unroll
        for (int j = 0; j < 2; ++j)
            acc[i][j] = (f32x16)(0.f);

    const int col = lane & 31, half = lane >> 5;
    const int wm = (wid & 1) * 64, wn = (wid >> 1) * 64;
    const int mf = wm + col, nf = wn + col;
    const int mswz = mf & 7, nswz = nf & 7;

    for (int k0 = 0; k0 < CH; k0 += 64) {
        #pragma unroll
        for (int g = 0; g < 4; ++g) {
            gload16(A + aoff + g * (32 * CH), lds_dst_a + g * 2048);
            gload16(B + boff + g * (32 * CH), lds_dst_b + g * 2048);
        }
        aoff += 64; boff += 64;
        __syncthreads();
        #pragma unroll
        for (int ks = 0; ks < 4; ++ks) {
            const int kcA = ((ks * 2 + half) ^ mswz) * 8;
            const int kcB = ((ks * 2 + half) ^ nswz) * 8;
            bf16x8 a0 = *(const bf16x8*)(As + (mf)      * 64 + kcA);
            bf16x8 a1 = *(const bf16x8*)(As + (mf + 32) * 64 + kcA);
            bf16x8 b0 = *(const bf16x8*)(Bs + (nf)      * 64 + kcB);
            bf16x8 b1 = *(const bf16x8*)(Bs + (nf + 32) * 64 + kcB);
            acc[0][0] = __builtin_amdgcn_mfma_f32_32x32x16_bf16(a0, b0, acc[0][0], 0, 0, 0);
            acc[0][1] = __builtin_amdgcn_mfma_f32_32x32x16_bf16(a0, b1, acc[0][1], 0, 0, 0);
            acc[1][0] = __builtin_amdgcn_mfma_f32_32x32x16_bf16(a1, b0, acc[1][0], 0, 0, 0);
            acc[1][1] = __builtin_amdgcn_mfma_f32_32x32x16_bf16(a1, b1, acc[1][1], 0, 0, 0);
        }
        __syncthreads();
    }

    if (!isV) {
        float* RS = rowsum + (size_t)bz * LEN;
        float psum[2] = {0.f, 0.f};
        #pragma unroll
        for (int im = 0; im < 2; ++im)
            #pragma unroll
            for (int g4 = 0; g4 < 4; ++g4) {
                const int mb = m0 + wm + im * 32 + g4 * 8 + half * 4;
                #pragma unroll
                for (int jn = 0; jn < 2; ++jn) {
                    const int n = n0 + wn + jn * 32 + col;
                    u16 h0 = f2bf(__expf(acc[im][jn][g4 * 4 + 0] * alpha));
                    u16 h1 = f2bf(__expf(acc[im][jn][g4 * 4 + 1] * alpha));
                    u16 h2 = f2bf(__expf(acc[im][jn][g4 * 4 + 2] * alpha));
                    u16 h3 = f2bf(__expf(acc[im][jn][g4 * 4 + 3] * alpha));
                    psum[jn] += bf2f(h0) + bf2f(h1) + bf2f(h2) + bf2f(h3);
                    *(ushort4*)&O[(size_t)n * LEN + mb] = make_ushort4(h0, h1, h2, h3);
                }
            }
        #pragma unroll
        for (int jn = 0; jn < 2; ++jn) psum[jn] += __shfl_xor(psum[jn], 32, 64);
        if (half == 0) {
            #pragma unroll
            for (int jn = 0; jn < 2; ++jn)
                atomicAdd(&RS[n0 + wn + jn * 32 + col], psum[jn]);
        }
    } else {
        #pragma unroll
        for (int im = 0; im < 2; ++im)
            #pragma unroll
            for (int g4 = 0; g4 < 4; ++g4) {
                const int mb = m0 + wm + im * 32 + g4 * 8 + half * 4;
                #pragma unroll
                for (int jn = 0; jn < 2; ++jn) {
                    const int n = n0 + wn + jn * 32 + col;
                    ushort4 pk = make_ushort4(f2bf(acc[im][jn][g4 * 4 + 0]),
                                              f2bf(acc[im][jn][g4 * 4 + 1]),
                                              f2bf(acc[im][jn][g4 * 4 + 2]),
                                              f2bf(acc[im][jn][g4 * 4 + 3]));
                    *(ushort4*)&O[(size_t)n * LEN + mb] = pk;
                }
            }
    }
}

// ---------------------------------------------------------------------------
extern "C" void kernel_launch(void* const* d_in, const int* in_sizes, int n_in,
                              void* d_out, int out_size, void* d_ws, size_t ws_size,
                              hipStream_t stream) {
    const float* x    = (const float*)d_in[0];
    const float* gn_w = (const float*)d_in[1];
    const float* gn_b = (const float*)d_in[2];
    const float* wq   = (const float*)d_in[3];
    const float* bq   = (const float*)d_in[4];
    const float* wk   = (const float*)d_in[5];
    const float* bk   = (const float*)d_in[6];
    const float* wv   = (const float*)d_in[7];
    const float* bv   = (const float*)d_in[8];
    const float* wo   = (const float*)d_in[9];
    const float* bo   = (const float*)d_in[10];
    float* out = (float*)d_out;

    char* p = (char*)d_ws;
    const size_t WSZ = (size_t)CH * CH * 2;
    const size_t HSZ = (size_t)BATCH * CH * LEN * 2;
    u16* Wqk = (u16*)p; p += 2 * WSZ;   // rows 0-511 = Wq, 512-1023 = Wk
    u16* Wov = (u16*)p; p += WSZ;       // (Wo.Wv) bf16 [o][c']
    float* biasp = (float*)p; p += WSZ; // bias' = Wo.bv + bo (512 f32)
    u16* Ht  = (u16*)p; p += HSZ;   // GN out [b][l][c]
    u16* Qt  = (u16*)p; p += HSZ;   // [b][l][c]
    u16* Kt  = (u16*)p; p += HSZ;   // [b][l][c]
    u16* Vb  = (u16*)p; p += HSZ;   // V' [b][o][l]
    u16* Sb  = (u16*)p; p += (size_t)BATCH * LEN * LEN * 2;  // exp(scores)
    float* rowsum = (float*)p; p += (size_t)BATCH * LEN * 4; // 16384 f32, zeroed
    float* stats  = (float*)p;      // 2048 f32: S partials | S2 partials

    const long long sH = (long long)LEN * CH;
    const long long sV = (long long)CH * LEN;
    const float scale = 0.04419417382415922f;   // 512^-0.5

    // Wov + bias' (own kernel -> own regalloc; r14 spill fix)
    wov_bias<<<258, 256, 0, stream>>>(wv, wo, bv, bo, Wov, biasp);
    // streaming pre-pass: zero(16) | wq/wk conv(512) | stats partials(1024)
    fused_pre<<<1552, 256, 0, stream>>>(x, wq, wk, Wqk, Wqk + (size_t)CH * CH,
                                        (float4*)rowsum, stats);
    gn_apply_t<<<dim3(LEN / 64, CH / 64, BATCH), 256, 0, stream>>>(x, stats, gn_w, gn_b, Ht);

    // Q+K fused: A=Wqk (m=o), B=Ht (n=l) -> Qt/Kt[l][o] packed in o
    gemm_bt<EPI_QK><<<dim3(16, 8, 8), 256, 0, stream>>>(
        Wqk, CH, 0, Ht, CH, sH, Qt, Kt, CH, sH, bq, bk, nullptr, 0, nullptr, 0, CH, 0.f);
    // scores (2048 blocks, XCD-remapped) + V' (512 blocks) in one launch
    gemm_sv<<<2560, 256, 0, stream>>>(Kt, Qt, Ht, Wov, Sb, Vb, rowsum, scale);
    // PV'' (replaces PV + final): A=Sb (m=i), B=V'b (n=o) ->
    //   out[o][i] = acc/rs[i] + bias'[o] + x[o][i]  (f32, residual fused)
    gemm_bt<EPI_PVF><<<dim3(4, 16, 8), 256, 0, stream>>>(
        Sb, LEN, (long long)LEN * LEN, Vb, LEN, sV, out, nullptr, LEN, sV,
        biasp, nullptr, x, sV, rowsum, LEN, LEN, 0.f);
}